// Round 3
// baseline (303.702 us; speedup 1.0000x reference)
//
#include <hip/hip_runtime.h>

// ---------------------------------------------------------------------------
// CausalSelfAttention: B=2, T=2048, C=1024, H=16, HD=64
// Inputs fp32, output fp32; internal bf16 MFMA.
// ---------------------------------------------------------------------------

#define B_   2
#define T_   2048
#define C_   1024
#define H_   16
#define HD_  64
#define BT_  (B_ * T_)      // 4096
#define C3_  (3 * C_)       // 3072

typedef __attribute__((ext_vector_type(8))) __bf16 bf16x8;
typedef __attribute__((ext_vector_type(4))) float  f32x4;
typedef __attribute__((ext_vector_type(8))) unsigned short u16x8;

__device__ __forceinline__ unsigned short f2bf(float f) {
    unsigned int u = __float_as_uint(f);
    u = (u + 0x7fffu + ((u >> 16) & 1u)) >> 16;
    return (unsigned short)u;
}

#define GLOAD16(g, l) __builtin_amdgcn_global_load_lds(                          \
    (const __attribute__((address_space(1))) unsigned int*)(g),                  \
    (__attribute__((address_space(3))) unsigned int*)(l), 16, 0, 0)

// ---------------- fp32 -> bf16 convert (8 elems/thread) --------------------
__global__ __launch_bounds__(256) void cvt_bf16(const float* __restrict__ in,
                                                unsigned short* __restrict__ out,
                                                int n8) {
    int i = blockIdx.x * 256 + threadIdx.x;
    if (i >= n8) return;
    const float4* p = (const float4*)in;
    float4 f0 = p[i * 2];
    float4 f1 = p[i * 2 + 1];
    u16x8 o;
    o[0] = f2bf(f0.x); o[1] = f2bf(f0.y); o[2] = f2bf(f0.z); o[3] = f2bf(f0.w);
    o[4] = f2bf(f1.x); o[5] = f2bf(f1.y); o[6] = f2bf(f1.z); o[7] = f2bf(f1.w);
    ((u16x8*)out)[i] = o;
}

// ---------------- bf16 GEMM: C[M][N] = A[M][K] * B[N][K]^T + bias ----------
// m97 structure: 128x128 tile, BK=64, global_load_lds dwordx4, linear LDS.
template<int OUT_BF16>
__global__ __launch_bounds__(256) void gemm_lds(const unsigned short* __restrict__ A,
                                                const unsigned short* __restrict__ Bm,
                                                const float* __restrict__ bias,
                                                void* __restrict__ Cv,
                                                int M, int N, int K) {
    __shared__ __align__(16) unsigned short As[128][64];
    __shared__ __align__(16) unsigned short Bs[128][64];

    const int t    = threadIdx.x;
    const int lane = t & 63;
    const int w    = t >> 6;
    const int wr   = w & 1;
    const int wc   = w >> 1;
    const int l15  = lane & 15;
    const int lhi  = lane >> 4;
    const int m0   = blockIdx.y * 128;
    const int n0   = blockIdx.x * 128;
    const int lrow = lane >> 3;          // 0..7
    const int lcol = (lane & 7) * 8;     // 0,8,..,56

    f32x4 acc[4][4] = {};

    for (int kb = 0; kb < K; kb += 64) {
        __syncthreads();
        // async global -> LDS staging, 1KB per inst per wave (lane*16B linear)
        #pragma unroll
        for (int i = 0; i < 4; ++i) {
            int row = w * 32 + i * 8;
            GLOAD16(A  + (size_t)(m0 + row + lrow) * K + kb + lcol, &As[row][0]);
            GLOAD16(Bm + (size_t)(n0 + row + lrow) * K + kb + lcol, &Bs[row][0]);
        }
        __syncthreads();   // drains vmcnt (incl. lds-DMA) + lgkm
        #pragma unroll
        for (int kk = 0; kk < 2; ++kk) {
            bf16x8 af[4], bfm[4];
            #pragma unroll
            for (int m = 0; m < 4; ++m)
                af[m] = *(const bf16x8*)(&As[wr * 64 + m * 16 + l15][kk * 32 + lhi * 8]);
            #pragma unroll
            for (int n = 0; n < 4; ++n)
                bfm[n] = *(const bf16x8*)(&Bs[wc * 64 + n * 16 + l15][kk * 32 + lhi * 8]);
            #pragma unroll
            for (int m = 0; m < 4; ++m)
                #pragma unroll
                for (int n = 0; n < 4; ++n)
                    acc[m][n] = __builtin_amdgcn_mfma_f32_16x16x32_bf16(af[m], bfm[n], acc[m][n], 0, 0, 0);
        }
    }

    #pragma unroll
    for (int n = 0; n < 4; ++n) {
        int cg = n0 + wc * 64 + n * 16 + l15;
        float bv = bias[cg];
        #pragma unroll
        for (int m = 0; m < 4; ++m) {
            #pragma unroll
            for (int i = 0; i < 4; ++i) {
                int rg  = m0 + wr * 64 + m * 16 + lhi * 4 + i;
                float v = acc[m][n][i] + bv;
                if (OUT_BF16)
                    ((unsigned short*)Cv)[(size_t)rg * N + cg] = f2bf(v);
                else
                    ((float*)Cv)[(size_t)rg * N + cg] = v;
            }
        }
    }
}

// ---------------- causal flash attention -----------------------------------
// grid = (T/64, B*H); 4 waves x 16 q-rows; KV tiles of 128.
// LDS: K tile (aliased by P after a barrier) + transposed V = 35.8 KB -> 4 blk/CU.
// Async-stage: next tile's K/V loaded to regs during compute (T14).
__global__ __launch_bounds__(256, 4) void attn_fwd(const unsigned short* __restrict__ qkv,
                                                   unsigned short* __restrict__ y) {
    __shared__ __align__(16) unsigned short KPs[128][72];   // K tile; P aliases it
    __shared__ __align__(16) unsigned short Vt[64][136];    // V transposed [d][key]

    const int t    = threadIdx.x;
    const int lane = t & 63;
    const int wv   = t >> 6;
    const int l15  = lane & 15;
    const int lhi  = lane >> 4;
    const int b    = blockIdx.y >> 4;
    const int h    = blockIdx.y & 15;
    const int qt   = gridDim.x - 1 - blockIdx.x;  // biggest tiles first
    const int q0   = qt * 64;
    const size_t rowbase = (size_t)b * T_ * C3_;
    const int hoff = h * HD_;
    unsigned short* PsW = &KPs[0][0] + wv * (16 * 136);  // wave-private P: 16x136

    // Q fragments in registers for the whole kernel
    bf16x8 qf[2];
    {
        int qrow = q0 + wv * 16 + l15;
        const unsigned short* qp = qkv + rowbase + (size_t)qrow * C3_ + hoff + lhi * 8;
        qf[0] = *(const bf16x8*)(qp);
        qf[1] = *(const bf16x8*)(qp + 32);
    }

    float Mx[4], Lx[4];
    f32x4 oacc[4];
    #pragma unroll
    for (int i = 0; i < 4; ++i) { Mx[i] = -1e30f; Lx[i] = 0.f; }
    #pragma unroll
    for (int n = 0; n < 4; ++n) oacc[n] = f32x4{0.f, 0.f, 0.f, 0.f};

    const unsigned short* kbase = qkv + rowbase + C_ + hoff;
    const unsigned short* vcol  = qkv + rowbase + 2 * C_ + hoff + lane;

    const int niter = (qt + 2) >> 1;

    // prologue: tile 0 -> regs
    uint4 kreg[4];
    u16x8 vreg[4];
    #pragma unroll
    for (int i = 0; i < 4; ++i) {
        int g = i * 256 + t;
        kreg[i] = *(const uint4*)(kbase + (size_t)(g >> 3) * C3_ + (g & 7) * 8);
    }
    #pragma unroll
    for (int pp = 0; pp < 4; ++pp) {
        int kb = pp * 32 + wv * 8;
        #pragma unroll
        for (int j = 0; j < 8; ++j)
            vreg[pp][j] = vcol[(size_t)(kb + j) * C3_];
    }

    for (int it = 0; it < niter; ++it) {
        const int k0 = it * 128;
        __syncthreads();                                   // [A] prev P/V reads done
        // regs -> LDS
        #pragma unroll
        for (int i = 0; i < 4; ++i) {
            int g = i * 256 + t;
            *(uint4*)(&KPs[g >> 3][(g & 7) * 8]) = kreg[i];
        }
        #pragma unroll
        for (int pp = 0; pp < 4; ++pp)
            *(u16x8*)(&Vt[lane][pp * 32 + wv * 8]) = vreg[pp];
        __syncthreads();                                   // [B] tile ready

        // issue next tile's global loads (latency hides under compute)
        if (it + 1 < niter) {
            const int kn = k0 + 128;
            #pragma unroll
            for (int i = 0; i < 4; ++i) {
                int g = i * 256 + t;
                kreg[i] = *(const uint4*)(kbase + (size_t)(kn + (g >> 3)) * C3_ + (g & 7) * 8);
            }
            #pragma unroll
            for (int pp = 0; pp < 4; ++pp) {
                int kb = kn + pp * 32 + wv * 8;
                #pragma unroll
                for (int j = 0; j < 8; ++j)
                    vreg[pp][j] = vcol[(size_t)(kb + j) * C3_];
            }
        }

        // S = Q K^T  (16 q-rows x 128 keys per wave)
        f32x4 sacc[8];
        #pragma unroll
        for (int n = 0; n < 8; ++n) sacc[n] = f32x4{0.f, 0.f, 0.f, 0.f};
        __builtin_amdgcn_s_setprio(1);
        #pragma unroll
        for (int kk = 0; kk < 2; ++kk) {
            #pragma unroll
            for (int n = 0; n < 8; ++n) {
                bf16x8 kf = *(const bf16x8*)(&KPs[n * 16 + l15][kk * 32 + lhi * 8]);
                sacc[n] = __builtin_amdgcn_mfma_f32_16x16x32_bf16(qf[kk], kf, sacc[n], 0, 0, 0);
            }
        }
        __builtin_amdgcn_s_setprio(0);
        __syncthreads();                                   // [C] all K reads done -> P may overwrite

        // scale + causal mask in place
        if (k0 + 127 <= q0) {
            #pragma unroll
            for (int n = 0; n < 8; ++n)
                #pragma unroll
                for (int i = 0; i < 4; ++i)
                    sacc[n][i] *= 0.125f;
        } else {
            const int qgb = q0 + wv * 16 + lhi * 4;
            #pragma unroll
            for (int n = 0; n < 8; ++n) {
                int kg = k0 + n * 16 + l15;
                #pragma unroll
                for (int i = 0; i < 4; ++i)
                    sacc[n][i] = (kg <= qgb + i) ? sacc[n][i] * 0.125f : -1e30f;
            }
        }

        // online softmax (row reductions across 16 lanes), in place
        #pragma unroll
        for (int i = 0; i < 4; ++i) {
            float vm = sacc[0][i];
            #pragma unroll
            for (int n = 1; n < 8; ++n) vm = fmaxf(vm, sacc[n][i]);
            vm = fmaxf(vm, __shfl_xor(vm, 1));
            vm = fmaxf(vm, __shfl_xor(vm, 2));
            vm = fmaxf(vm, __shfl_xor(vm, 4));
            vm = fmaxf(vm, __shfl_xor(vm, 8));
            float Mn = fmaxf(Mx[i], vm);
            float al = __expf(Mx[i] - Mn);
            Mx[i] = Mn;
            float rs = 0.f;
            #pragma unroll
            for (int n = 0; n < 8; ++n) {
                float e = __expf(sacc[n][i] - Mn);
                sacc[n][i] = e;
                rs += e;
            }
            rs += __shfl_xor(rs, 1);
            rs += __shfl_xor(rs, 2);
            rs += __shfl_xor(rs, 4);
            rs += __shfl_xor(rs, 8);
            Lx[i] = Lx[i] * al + rs;
            #pragma unroll
            for (int n = 0; n < 4; ++n) oacc[n][i] *= al;
        }

        // P -> LDS (wave-private region aliasing K tile)
        #pragma unroll
        for (int n = 0; n < 8; ++n)
            #pragma unroll
            for (int i = 0; i < 4; ++i)
                PsW[(lhi * 4 + i) * 136 + n * 16 + l15] = f2bf(sacc[n][i]);
        asm volatile("s_waitcnt lgkmcnt(0)" ::: "memory");

        __builtin_amdgcn_s_setprio(1);
        #pragma unroll
        for (int kk = 0; kk < 4; ++kk) {
            bf16x8 pf = *(const bf16x8*)(PsW + l15 * 136 + kk * 32 + lhi * 8);
            #pragma unroll
            for (int nd = 0; nd < 4; ++nd) {
                bf16x8 vf = *(const bf16x8*)(&Vt[nd * 16 + l15][kk * 32 + lhi * 8]);
                oacc[nd] = __builtin_amdgcn_mfma_f32_16x16x32_bf16(pf, vf, oacc[nd], 0, 0, 0);
            }
        }
        __builtin_amdgcn_s_setprio(0);
    }

    // epilogue: O / L -> y (bf16, (B*T, C) layout)
    #pragma unroll
    for (int nd = 0; nd < 4; ++nd) {
        #pragma unroll
        for (int i = 0; i < 4; ++i) {
            int qg  = q0 + wv * 16 + lhi * 4 + i;
            float v = oacc[nd][i] / Lx[i];
            y[(size_t)(b * T_ + qg) * C_ + hoff + nd * 16 + l15] = f2bf(v);
        }
    }
}

// ---------------------------------------------------------------------------
extern "C" void kernel_launch(void* const* d_in, const int* in_sizes, int n_in,
                              void* d_out, int out_size, void* d_ws, size_t ws_size,
                              hipStream_t stream) {
    const float* x      = (const float*)d_in[0];
    const float* W_attn = (const float*)d_in[1];
    const float* b_attn = (const float*)d_in[2];
    const float* W_proj = (const float*)d_in[3];
    const float* b_proj = (const float*)d_in[4];
    float* out = (float*)d_out;

    char* ws = (char*)d_ws;
    unsigned short* xb   = (unsigned short*)(ws);                       // 4096x1024
    unsigned short* wab  = (unsigned short*)(ws + 8388608);             // 3072x1024
    unsigned short* wpb  = (unsigned short*)(ws + 8388608 + 6291456);   // 1024x1024
    unsigned short* qkvb = (unsigned short*)(ws + 16777216);            // 4096x3072
    unsigned short* yb   = (unsigned short*)(ws + 16777216 + 25165824); // 4096x1024

    cvt_bf16<<<(BT_ * C_ / 8 + 255) / 256, 256, 0, stream>>>(x, xb, BT_ * C_ / 8);
    cvt_bf16<<<(C3_ * C_ / 8 + 255) / 256, 256, 0, stream>>>(W_attn, wab, C3_ * C_ / 8);
    cvt_bf16<<<(C_ * C_ / 8 + 255) / 256, 256, 0, stream>>>(W_proj, wpb, C_ * C_ / 8);

    gemm_lds<1><<<dim3(C3_ / 128, BT_ / 128), 256, 0, stream>>>(xb, wab, b_attn, qkvb, BT_, C3_, C_);

    attn_fwd<<<dim3(T_ / 64, B_ * H_), 256, 0, stream>>>(qkvb, yb);

    gemm_lds<0><<<dim3(C_ / 128, BT_ / 128), 256, 0, stream>>>(yb, wpb, b_proj, out, BT_, C_, C_);
}